// Round 7
// baseline (207.613 us; speedup 1.0000x reference)
//
#include <hip/hip_runtime.h>
#include <hip/hip_bf16.h>
#include <math.h>

#define N_NODES 10000
#define N_EDGES 120000
#define ET (N_EDGES + N_NODES)   // edges + self loops
#define IN_DIM 256
#define H_HEADS 8
#define C_DIM 128
#define NN_DIM (H_HEADS * C_DIM) // 1024
#define G_GRAPHS 64
#define EPS_BN 1e-5f
#define SLOPE 0.2f

typedef unsigned short u16;
typedef __attribute__((ext_vector_type(8))) short bf16x8;
typedef __attribute__((ext_vector_type(4))) float f32x4;

__device__ __forceinline__ u16 f2b(float f) {            // RNE float->bf16
    unsigned int u = __float_as_uint(f);
    unsigned int r = (u + 0x7fffu + ((u >> 16) & 1u)) >> 16;
    return (u16)r;
}
__device__ __forceinline__ float b2f(u16 u) {
    return __uint_as_float(((unsigned int)u) << 16);
}

// ---------------- fused prep: x->bf16, W->Wt bf16, degree count, graph starts ----------------
#define XB_BLOCKS 2500                        // N*IN/4/256
#define WT1_TILES 256                         // (1024/32)*(256/32)
#define WT23_TILES 128                        // (1024/32)*(128/32)
#define CNT_BLOCKS ((ET + 255) / 256)         // 508
#define ST_BLOCKS ((N_NODES + 255) / 256)     // 40
#define PREP_B0 XB_BLOCKS
#define PREP_B1 (PREP_B0 + WT1_TILES)
#define PREP_B2 (PREP_B1 + WT23_TILES)
#define PREP_B3 (PREP_B2 + WT23_TILES)
#define PREP_B4 (PREP_B3 + CNT_BLOCKS)
#define PREP_B5 (PREP_B4 + ST_BLOCKS)

__device__ __forceinline__ void wt_tile(const float* __restrict__ W, u16* __restrict__ Wt,
                                        int K, int t, int tid, float (*sh)[33]) {
    int bn = (t & 31) * 32;
    int bk = (t >> 5) * 32;
    int tx = tid & 31, ty = tid >> 5;
    for (int r = ty; r < 32; r += 8)
        sh[r][tx] = W[(size_t)(bk + r) * NN_DIM + bn + tx];   // sh[k][n]
    __syncthreads();
    for (int r = ty; r < 32; r += 8)
        Wt[(size_t)(bn + r) * K + bk + tx] = f2b(sh[tx][r]);  // Wt[n][k]
}

__global__ __launch_bounds__(256) void k_prep(const float* __restrict__ x, u16* __restrict__ xb,
                                              const float* __restrict__ W1, u16* __restrict__ wt1,
                                              const float* __restrict__ W2, u16* __restrict__ wt2,
                                              const float* __restrict__ W3, u16* __restrict__ wt3,
                                              const int* __restrict__ ei, int* __restrict__ deg,
                                              const int* __restrict__ batch, int* __restrict__ starts) {
    __shared__ float sh[32][33];
    int b = blockIdx.x, tid = threadIdx.x;
    if (b < PREP_B0) {
        int i = b * 256 + tid;                 // one float4 per thread
        float4 v = reinterpret_cast<const float4*>(x)[i];
        unsigned int lo = (unsigned int)f2b(v.x) | ((unsigned int)f2b(v.y) << 16);
        unsigned int hi = (unsigned int)f2b(v.z) | ((unsigned int)f2b(v.w) << 16);
        reinterpret_cast<uint2*>(xb)[i] = make_uint2(lo, hi);
    } else if (b < PREP_B1) {
        wt_tile(W1, wt1, IN_DIM, b - PREP_B0, tid, sh);
    } else if (b < PREP_B2) {
        wt_tile(W2, wt2, C_DIM, b - PREP_B1, tid, sh);
    } else if (b < PREP_B3) {
        wt_tile(W3, wt3, C_DIM, b - PREP_B2, tid, sh);
    } else if (b < PREP_B4) {
        int e = (b - PREP_B3) * 256 + tid;
        if (e < ET) {
            int d = (e < N_EDGES) ? ei[N_EDGES + e] : (e - N_EDGES);
            atomicAdd(&deg[d], 1);
        }
    } else {
        int i = (b - PREP_B4) * 256 + tid;
        if (i < N_NODES) {
            if (i == 0) starts[batch[0]] = 0;
            else if (batch[i] != batch[i - 1]) starts[batch[i]] = i;
            if (i == N_NODES - 1) starts[G_GRAPHS] = N_NODES;
        }
    }
}

// ---------------- single-block exclusive scan (wave shfl, 2 barriers/chunk) ----------------
__global__ __launch_bounds__(1024) void k_scan(const int* __restrict__ deg, int* __restrict__ row_ptr) {
    __shared__ int ws[16];
    __shared__ int stot;
    int tid = threadIdx.x, lane = tid & 63, wid = tid >> 6;
    int carry = 0;
    for (int base = 0; base < N_NODES; base += 1024) {
        int i = base + tid;
        int v = (i < N_NODES) ? deg[i] : 0;
        int xv = v;
        #pragma unroll
        for (int off = 1; off < 64; off <<= 1) {
            int y = __shfl_up(xv, off, 64);
            if (lane >= off) xv += y;
        }
        if (lane == 63) ws[wid] = xv;
        __syncthreads();
        if (wid == 0) {
            int t = (lane < 16) ? ws[lane] : 0;
            #pragma unroll
            for (int off = 1; off < 16; off <<= 1) {
                int y = __shfl_up(t, off, 64);
                if (lane >= off) t += y;
            }
            if (lane < 16) ws[lane] = t;
            if (lane == 15) stot = t;
        }
        __syncthreads();
        int wpref = (wid > 0) ? ws[wid - 1] : 0;
        if (i < N_NODES) row_ptr[i] = carry + wpref + xv - v;   // exclusive
        carry += stot;
        __syncthreads();    // protect ws/stot before next chunk
    }
    if (tid == 0) row_ptr[N_NODES] = carry;
}

__global__ void k_scatter(const int* __restrict__ ei, const int* __restrict__ row_ptr,
                          int* __restrict__ cursor, int* __restrict__ csr_src) {
    int e = blockIdx.x * blockDim.x + threadIdx.x;
    if (e >= ET) return;
    int s, d;
    if (e < N_EDGES) { s = ei[e]; d = ei[N_EDGES + e]; }
    else             { s = e - N_EDGES; d = s; }
    int pos = atomicAdd(&cursor[d], 1);
    csr_src[row_ptr[d] + pos] = s;
}

// ---------------- bf16 MFMA GEMM + fused es/ed epilogue ----------------
// head-major output: h[hd][n][c]; es[hd][n], ed[hd][n]; blockIdx.y == head
__global__ __launch_bounds__(256) void k_gemm_mfma(const u16* __restrict__ A,
                                                   const u16* __restrict__ Bt,
                                                   const float* __restrict__ a_s,
                                                   const float* __restrict__ a_d,
                                                   u16* __restrict__ C,
                                                   float* __restrict__ es,
                                                   float* __restrict__ ed,
                                                   int M, int K) {
    __shared__ u16 As[128 * 32];
    __shared__ u16 Bs[128 * 32];
    __shared__ float esb[2][128];
    __shared__ float edb[2][128];
    int tid = threadIdx.x;
    int wave = tid >> 6, lane = tid & 63;
    int wr = wave >> 1, wc = wave & 1;
    int bm = blockIdx.x * 128;
    int bn = blockIdx.y * 128;
    int hd = blockIdx.y;
    f32x4 acc[4][4] = {};

    for (int k0 = 0; k0 < K; k0 += 32) {
        #pragma unroll
        for (int cc = 0; cc < 2; cc++) {
            int ch = wave + cc * 4;                 // 8 chunks of 16 rows
            int row = ch * 16 + (lane >> 2);
            int gr = bm + row; if (gr >= M) gr = M - 1;
            const u16* gp = &A[(size_t)gr * K + k0 + (lane & 3) * 8];
            __builtin_amdgcn_global_load_lds((const __attribute__((address_space(1))) unsigned int*)gp,
                (__attribute__((address_space(3))) unsigned int*)&As[ch * 512], 16, 0, 0);
            const u16* gq = &Bt[(size_t)(bn + row) * K + k0 + (lane & 3) * 8];
            __builtin_amdgcn_global_load_lds((const __attribute__((address_space(1))) unsigned int*)gq,
                (__attribute__((address_space(3))) unsigned int*)&Bs[ch * 512], 16, 0, 0);
        }
        __syncthreads();
        bf16x8 af[4], bfr[4];
        #pragma unroll
        for (int mf = 0; mf < 4; mf++)
            af[mf] = *reinterpret_cast<const bf16x8*>(&As[(wr * 64 + mf * 16 + (lane & 15)) * 32 + (lane >> 4) * 8]);
        #pragma unroll
        for (int nf = 0; nf < 4; nf++)
            bfr[nf] = *reinterpret_cast<const bf16x8*>(&Bs[(wc * 64 + nf * 16 + (lane & 15)) * 32 + (lane >> 4) * 8]);
        #pragma unroll
        for (int mf = 0; mf < 4; mf++)
            #pragma unroll
            for (int nf = 0; nf < 4; nf++)
                acc[mf][nf] = __builtin_amdgcn_mfma_f32_16x16x32_bf16(af[mf], bfr[nf], acc[mf][nf], 0, 0, 0);
        __syncthreads();
    }

    // epilogue: bf16 C write (head-major) + per-row dot with a_s/a_d
    float as_v[4], ad_v[4];
    #pragma unroll
    for (int nf = 0; nf < 4; nf++) {
        int colh = wc * 64 + nf * 16 + (lane & 15);
        as_v[nf] = a_s[hd * C_DIM + colh];
        ad_v[nf] = a_d[hd * C_DIM + colh];
    }
    u16* Ch = C + (size_t)hd * M * C_DIM;
    #pragma unroll
    for (int mf = 0; mf < 4; mf++) {
        #pragma unroll
        for (int i = 0; i < 4; i++) {
            int rl = wr * 64 + mf * 16 + (lane >> 4) * 4 + i;
            int row = bm + rl;
            float se = 0.f, de = 0.f;
            #pragma unroll
            for (int nf = 0; nf < 4; nf++) {
                u16 hb = f2b(acc[mf][nf][i]);
                float vb = b2f(hb);
                se += vb * as_v[nf];
                de += vb * ad_v[nf];
                if (row < M) Ch[(size_t)row * C_DIM + wc * 64 + nf * 16 + (lane & 15)] = hb;
            }
            #pragma unroll
            for (int off = 8; off; off >>= 1) { se += __shfl_xor(se, off); de += __shfl_xor(de, off); }
            if ((lane & 15) == 0) { esb[wc][rl] = se; edb[wc][rl] = de; }
        }
    }
    __syncthreads();
    if (tid < 128) {
        int row = bm + tid;
        if (row < M) {
            es[(size_t)hd * M + row] = esb[0][tid] + esb[1][tid];
            ed[(size_t)hd * M + row] = edb[0][tid] + edb[1][tid];
        }
    }
}

// ---------------- head-affine GAT gather: single-pass, no max-sub ----------------
// softmax is invariant to max subtraction; |alpha| <~ 3 here so exp() is safe in fp32.
// grid (8, N/16); blockIdx.x = head (fastest-varying -> one head per XCD)
__global__ __launch_bounds__(256) void k_gat(const u16* __restrict__ h,
                                             const float* __restrict__ es,
                                             const float* __restrict__ ed,
                                             const int* __restrict__ row_ptr,
                                             const int* __restrict__ csr_src,
                                             u16* __restrict__ part) {
    int hd = blockIdx.x;
    int g = threadIdx.x >> 4;     // 16 groups
    int lane = threadIdx.x & 15;  // 16 lanes per group: 8 channels each
    int n = blockIdx.y * 16 + g;
    const u16* hh = h + (size_t)hd * N_NODES * C_DIM;
    const float* esh = es + (size_t)hd * N_NODES;
    float edv = ed[(size_t)hd * N_NODES + n];
    int s = row_ptr[n];
    int deg = row_ptr[n + 1] - s;

    __shared__ int s_src[16][16];
    __shared__ float s_p[16][16];

    float den = 0.f;
    float acc[8] = {0.f, 0.f, 0.f, 0.f, 0.f, 0.f, 0.f, 0.f};

    for (int j0 = 0; j0 < deg; j0 += 16) {
        int cn = deg - j0; if (cn > 16) cn = 16;
        if (lane < cn) {
            int src = csr_src[s + j0 + lane];
            s_src[g][lane] = src;
            float a = esh[src] + edv;
            a = (a > 0.f) ? a : SLOPE * a;
            float p = __expf(a);
            s_p[g][lane] = p;
            den += p;
        }
        int j = 0;
        for (; j + 8 <= cn; j += 8) {
            uint4 v0 = *reinterpret_cast<const uint4*>(&hh[(size_t)s_src[g][j + 0] * C_DIM + lane * 8]);
            uint4 v1 = *reinterpret_cast<const uint4*>(&hh[(size_t)s_src[g][j + 1] * C_DIM + lane * 8]);
            uint4 v2 = *reinterpret_cast<const uint4*>(&hh[(size_t)s_src[g][j + 2] * C_DIM + lane * 8]);
            uint4 v3 = *reinterpret_cast<const uint4*>(&hh[(size_t)s_src[g][j + 3] * C_DIM + lane * 8]);
            uint4 v4 = *reinterpret_cast<const uint4*>(&hh[(size_t)s_src[g][j + 4] * C_DIM + lane * 8]);
            uint4 v5 = *reinterpret_cast<const uint4*>(&hh[(size_t)s_src[g][j + 5] * C_DIM + lane * 8]);
            uint4 v6 = *reinterpret_cast<const uint4*>(&hh[(size_t)s_src[g][j + 6] * C_DIM + lane * 8]);
            uint4 v7 = *reinterpret_cast<const uint4*>(&hh[(size_t)s_src[g][j + 7] * C_DIM + lane * 8]);
            float p0 = s_p[g][j + 0], p1 = s_p[g][j + 1], p2 = s_p[g][j + 2], p3 = s_p[g][j + 3];
            float p4 = s_p[g][j + 4], p5 = s_p[g][j + 5], p6 = s_p[g][j + 6], p7 = s_p[g][j + 7];
            acc[0] += p0 * b2f((u16)v0.x) + p1 * b2f((u16)v1.x) + p2 * b2f((u16)v2.x) + p3 * b2f((u16)v3.x)
                    + p4 * b2f((u16)v4.x) + p5 * b2f((u16)v5.x) + p6 * b2f((u16)v6.x) + p7 * b2f((u16)v7.x);
            acc[1] += p0 * b2f((u16)(v0.x >> 16)) + p1 * b2f((u16)(v1.x >> 16)) + p2 * b2f((u16)(v2.x >> 16)) + p3 * b2f((u16)(v3.x >> 16))
                    + p4 * b2f((u16)(v4.x >> 16)) + p5 * b2f((u16)(v5.x >> 16)) + p6 * b2f((u16)(v6.x >> 16)) + p7 * b2f((u16)(v7.x >> 16));
            acc[2] += p0 * b2f((u16)v0.y) + p1 * b2f((u16)v1.y) + p2 * b2f((u16)v2.y) + p3 * b2f((u16)v3.y)
                    + p4 * b2f((u16)v4.y) + p5 * b2f((u16)v5.y) + p6 * b2f((u16)v6.y) + p7 * b2f((u16)v7.y);
            acc[3] += p0 * b2f((u16)(v0.y >> 16)) + p1 * b2f((u16)(v1.y >> 16)) + p2 * b2f((u16)(v2.y >> 16)) + p3 * b2f((u16)(v3.y >> 16))
                    + p4 * b2f((u16)(v4.y >> 16)) + p5 * b2f((u16)(v5.y >> 16)) + p6 * b2f((u16)(v6.y >> 16)) + p7 * b2f((u16)(v7.y >> 16));
            acc[4] += p0 * b2f((u16)v0.z) + p1 * b2f((u16)v1.z) + p2 * b2f((u16)v2.z) + p3 * b2f((u16)v3.z)
                    + p4 * b2f((u16)v4.z) + p5 * b2f((u16)v5.z) + p6 * b2f((u16)v6.z) + p7 * b2f((u16)v7.z);
            acc[5] += p0 * b2f((u16)(v0.z >> 16)) + p1 * b2f((u16)(v1.z >> 16)) + p2 * b2f((u16)(v2.z >> 16)) + p3 * b2f((u16)(v3.z >> 16))
                    + p4 * b2f((u16)(v4.z >> 16)) + p5 * b2f((u16)(v5.z >> 16)) + p6 * b2f((u16)(v6.z >> 16)) + p7 * b2f((u16)(v7.z >> 16));
            acc[6] += p0 * b2f((u16)v0.w) + p1 * b2f((u16)v1.w) + p2 * b2f((u16)v2.w) + p3 * b2f((u16)v3.w)
                    + p4 * b2f((u16)v4.w) + p5 * b2f((u16)v5.w) + p6 * b2f((u16)v6.w) + p7 * b2f((u16)v7.w);
            acc[7] += p0 * b2f((u16)(v0.w >> 16)) + p1 * b2f((u16)(v1.w >> 16)) + p2 * b2f((u16)(v2.w >> 16)) + p3 * b2f((u16)(v3.w >> 16))
                    + p4 * b2f((u16)(v4.w >> 16)) + p5 * b2f((u16)(v5.w >> 16)) + p6 * b2f((u16)(v6.w >> 16)) + p7 * b2f((u16)(v7.w >> 16));
        }
        for (; j + 4 <= cn; j += 4) {
            uint4 v0 = *reinterpret_cast<const uint4*>(&hh[(size_t)s_src[g][j + 0] * C_DIM + lane * 8]);
            uint4 v1 = *reinterpret_cast<const uint4*>(&hh[(size_t)s_src[g][j + 1] * C_DIM + lane * 8]);
            uint4 v2 = *reinterpret_cast<const uint4*>(&hh[(size_t)s_src[g][j + 2] * C_DIM + lane * 8]);
            uint4 v3 = *reinterpret_cast<const uint4*>(&hh[(size_t)s_src[g][j + 3] * C_DIM + lane * 8]);
            float p0 = s_p[g][j + 0], p1 = s_p[g][j + 1], p2 = s_p[g][j + 2], p3 = s_p[g][j + 3];
            acc[0] += p0 * b2f((u16)v0.x) + p1 * b2f((u16)v1.x) + p2 * b2f((u16)v2.x) + p3 * b2f((u16)v3.x);
            acc[1] += p0 * b2f((u16)(v0.x >> 16)) + p1 * b2f((u16)(v1.x >> 16)) + p2 * b2f((u16)(v2.x >> 16)) + p3 * b2f((u16)(v3.x >> 16));
            acc[2] += p0 * b2f((u16)v0.y) + p1 * b2f((u16)v1.y) + p2 * b2f((u16)v2.y) + p3 * b2f((u16)v3.y);
            acc[3] += p0 * b2f((u16)(v0.y >> 16)) + p1 * b2f((u16)(v1.y >> 16)) + p2 * b2f((u16)(v2.y >> 16)) + p3 * b2f((u16)(v3.y >> 16));
            acc[4] += p0 * b2f((u16)v0.z) + p1 * b2f((u16)v1.z) + p2 * b2f((u16)v2.z) + p3 * b2f((u16)v3.z);
            acc[5] += p0 * b2f((u16)(v0.z >> 16)) + p1 * b2f((u16)(v1.z >> 16)) + p2 * b2f((u16)(v2.z >> 16)) + p3 * b2f((u16)(v3.z >> 16));
            acc[6] += p0 * b2f((u16)v0.w) + p1 * b2f((u16)v1.w) + p2 * b2f((u16)v2.w) + p3 * b2f((u16)v3.w);
            acc[7] += p0 * b2f((u16)(v0.w >> 16)) + p1 * b2f((u16)(v1.w >> 16)) + p2 * b2f((u16)(v2.w >> 16)) + p3 * b2f((u16)(v3.w >> 16));
        }
        for (; j < cn; j++) {
            int sr = s_src[g][j];
            float p = s_p[g][j];
            uint4 v = *reinterpret_cast<const uint4*>(&hh[(size_t)sr * C_DIM + lane * 8]);
            acc[0] += p * b2f((u16)v.x);
            acc[1] += p * b2f((u16)(v.x >> 16));
            acc[2] += p * b2f((u16)v.y);
            acc[3] += p * b2f((u16)(v.y >> 16));
            acc[4] += p * b2f((u16)v.z);
            acc[5] += p * b2f((u16)(v.z >> 16));
            acc[6] += p * b2f((u16)v.w);
            acc[7] += p * b2f((u16)(v.w >> 16));
        }
    }
    #pragma unroll
    for (int off = 8; off; off >>= 1) den += __shfl_xor(den, off, 16);
    float inv = 1.f / den;
    unsigned int w0 = (unsigned int)f2b(acc[0] * inv) | ((unsigned int)f2b(acc[1] * inv) << 16);
    unsigned int w1 = (unsigned int)f2b(acc[2] * inv) | ((unsigned int)f2b(acc[3] * inv) << 16);
    unsigned int w2 = (unsigned int)f2b(acc[4] * inv) | ((unsigned int)f2b(acc[5] * inv) << 16);
    unsigned int w3 = (unsigned int)f2b(acc[6] * inv) | ((unsigned int)f2b(acc[7] * inv) << 16);
    *reinterpret_cast<uint4*>(&part[((size_t)hd * N_NODES + n) * C_DIM + lane * 8]) =
        make_uint4(w0, w1, w2, w3);
}

// ---------------- head-sum + mean + bias + relu + BN -> feat (bf16) ----------------
__global__ __launch_bounds__(256) void k_hsum(const u16* __restrict__ part,
                                              const float* __restrict__ bias,
                                              const float* __restrict__ gamma,
                                              const float* __restrict__ beta,
                                              const float* __restrict__ rmean,
                                              const float* __restrict__ rvar,
                                              u16* __restrict__ feat) {
    int idx = blockIdx.x * blockDim.x + threadIdx.x;   // one per (n, 4-ch quad)
    int n = idx >> 5;
    int q = idx & 31;
    int c = q * 4;
    float s0 = 0.f, s1 = 0.f, s2 = 0.f, s3 = 0.f;
    #pragma unroll
    for (int hd = 0; hd < H_HEADS; hd++) {
        uint2 v = *reinterpret_cast<const uint2*>(&part[((size_t)hd * N_NODES + n) * C_DIM + c]);
        s0 += b2f((u16)v.x); s1 += b2f((u16)(v.x >> 16));
        s2 += b2f((u16)v.y); s3 += b2f((u16)(v.y >> 16));
    }
    float4 bi = *reinterpret_cast<const float4*>(&bias[c]);
    float4 ga = *reinterpret_cast<const float4*>(&gamma[c]);
    float4 be = *reinterpret_cast<const float4*>(&beta[c]);
    float4 mu = *reinterpret_cast<const float4*>(&rmean[c]);
    float4 va = *reinterpret_cast<const float4*>(&rvar[c]);
    float v0 = fmaxf(s0 * 0.125f + bi.x, 0.f);
    float v1 = fmaxf(s1 * 0.125f + bi.y, 0.f);
    float v2 = fmaxf(s2 * 0.125f + bi.z, 0.f);
    float v3 = fmaxf(s3 * 0.125f + bi.w, 0.f);
    v0 = (v0 - mu.x) * rsqrtf(va.x + EPS_BN) * ga.x + be.x;
    v1 = (v1 - mu.y) * rsqrtf(va.y + EPS_BN) * ga.y + be.y;
    v2 = (v2 - mu.z) * rsqrtf(va.z + EPS_BN) * ga.z + be.z;
    v3 = (v3 - mu.w) * rsqrtf(va.w + EPS_BN) * ga.w + be.w;
    unsigned int lo = (unsigned int)f2b(v0) | ((unsigned int)f2b(v1) << 16);
    unsigned int hi = (unsigned int)f2b(v2) | ((unsigned int)f2b(v3) << 16);
    *reinterpret_cast<uint2*>(&feat[(size_t)n * C_DIM + c]) = make_uint2(lo, hi);
}

// ---------------- fused pooling + MLP head: 1024 threads, 8-way k-split ----------------
__global__ __launch_bounds__(1024) void k_poolhead(const u16* __restrict__ feat,
                                                   const float* __restrict__ x,
                                                   const int* __restrict__ starts,
                                                   const float* __restrict__ l0W, const float* __restrict__ l0b,
                                                   const float* __restrict__ lnW, const float* __restrict__ lnb,
                                                   const float* __restrict__ l1W, const float* __restrict__ l1b,
                                                   float* __restrict__ outp) {
    int g = blockIdx.x;
    int tid = threadIdx.x;
    int part = tid >> 7;               // 0..7
    int c = tid & 127;
    int s = starts[g], e = starts[g + 1];

    __shared__ float smx[8][128], ssm[8][128];
    __shared__ float pg[256];
    __shared__ float xr[256];
    __shared__ float sh2[2];

    // pooling: 8-way strided over nodes
    float mx = -1e30f, sm = 0.f;
    for (int i = s + part; i < e; i += 8) {
        float v = b2f(feat[(size_t)i * C_DIM + c]);
        mx = fmaxf(mx, v);
        sm += v;
    }
    smx[part][c] = mx;
    ssm[part][c] = sm;
    if (tid < 256) xr[tid] = x[(size_t)s * IN_DIM + tid];   // root row
    __syncthreads();
    if (part == 0) {
        float m = smx[0][c], t = ssm[0][c];
        #pragma unroll
        for (int p2 = 1; p2 < 8; p2++) { m = fmaxf(m, smx[p2][c]); t += ssm[p2][c]; }
        pg[c] = m;
        pg[128 + c] = t / (float)(e - s);
    }
    __syncthreads();

    // head GEMMs: k-split 8 x 32
    float acc0 = 0.f, acc1 = 0.f;
    int k0 = part * 32;
    #pragma unroll 8
    for (int k = k0; k < k0 + 32; k++) {
        acc0 += pg[k] * l0W[k * C_DIM + c];
        acc1 += xr[k] * lnW[k * C_DIM + c];
    }
    __syncthreads();                     // pg/xr reads done; reuse smx/ssm
    smx[part][c] = acc0;
    ssm[part][c] = acc1;
    __syncthreads();
    if (part == 0) {                     // first 2 waves finish
        float a0 = 0.f, a1 = 0.f;
        #pragma unroll
        for (int p2 = 0; p2 < 8; p2++) { a0 += smx[p2][c]; a1 += ssm[p2][c]; }
        float hg = fmaxf(a0 + l0b[c], 0.f);
        float nw = fmaxf(a1 + lnb[c], 0.f);
        float prt = hg * l1W[c] + nw * l1W[C_DIM + c];
        #pragma unroll
        for (int off = 32; off; off >>= 1) prt += __shfl_down(prt, off, 64);
        if ((c & 63) == 0) sh2[c >> 6] = prt;
    }
    __syncthreads();
    if (tid == 0) {
        float t = sh2[0] + sh2[1] + l1b[0];
        outp[g] = 1.f / (1.f + __expf(-t));
    }
}

extern "C" void kernel_launch(void* const* d_in, const int* in_sizes, int n_in,
                              void* d_out, int out_size, void* d_ws, size_t ws_size,
                              hipStream_t stream) {
    const float* x   = (const float*)d_in[0];
    const int* ei    = (const int*)d_in[1];
    const int* batch = (const int*)d_in[2];
    const float* W[3];  const float* As_[3]; const float* Ad_[3];
    const float* Bi[3]; const float* Ga[3]; const float* Be[3];
    const float* Mu[3]; const float* Va[3];
    for (int l = 0; l < 3; l++) {
        int base = 3 + 8 * l;
        W[l]   = (const float*)d_in[base + 0];
        As_[l] = (const float*)d_in[base + 1];
        Ad_[l] = (const float*)d_in[base + 2];
        Bi[l]  = (const float*)d_in[base + 3];
        Ga[l]  = (const float*)d_in[base + 4];
        Be[l]  = (const float*)d_in[base + 5];
        Mu[l]  = (const float*)d_in[base + 6];
        Va[l]  = (const float*)d_in[base + 7];
    }
    const float* lnW = (const float*)d_in[27];
    const float* lnb = (const float*)d_in[28];
    const float* l0W = (const float*)d_in[29];
    const float* l0b = (const float*)d_in[30];
    const float* l1W = (const float*)d_in[31];
    const float* l1b = (const float*)d_in[32];
    float* outp = (float*)d_out;

    // workspace layout (all offsets 16B-aligned)
    char* p = (char*)d_ws;
    auto take = [&](size_t bytes) { char* q = p; p += (bytes + 15) & ~(size_t)15; return q; };
    u16*  h      = (u16*)take((size_t)N_NODES * NN_DIM * sizeof(u16));   // head-major [hd][n][c]
    u16*  part   = (u16*)take((size_t)N_NODES * NN_DIM * sizeof(u16));   // head-major partial out
    u16*  xb     = (u16*)take((size_t)N_NODES * IN_DIM * sizeof(u16));
    u16*  wt1    = (u16*)take((size_t)NN_DIM * IN_DIM * sizeof(u16));
    u16*  wt2    = (u16*)take((size_t)NN_DIM * C_DIM * sizeof(u16));
    u16*  wt3    = (u16*)take((size_t)NN_DIM * C_DIM * sizeof(u16));
    u16*  feat_a = (u16*)take((size_t)N_NODES * C_DIM * sizeof(u16));
    u16*  feat_b = (u16*)take((size_t)N_NODES * C_DIM * sizeof(u16));
    float* es    = (float*)take((size_t)N_NODES * H_HEADS * sizeof(float));  // [hd][n]
    float* ed    = (float*)take((size_t)N_NODES * H_HEADS * sizeof(float));  // [hd][n]
    int* deg     = (int*)take((size_t)N_NODES * sizeof(int));      // deg+cursor adjacent:
    int* cursor  = (int*)take((size_t)N_NODES * sizeof(int));      // single memset below
    int* row_ptr = (int*)take((size_t)(N_NODES + 1) * sizeof(int));
    int* csr_src = (int*)take((size_t)ET * sizeof(int));
    int* starts  = (int*)take((size_t)(G_GRAPHS + 1) * sizeof(int));

    hipMemsetAsync(deg, 0, 2 * N_NODES * sizeof(int), stream);   // deg + cursor

    // prep (x->bf16, Wt transposes, degree count, graph starts) + CSR
    k_prep<<<PREP_B5, 256, 0, stream>>>(x, xb, W[0], wt1, W[1], wt2, W[2], wt3,
                                        ei, deg, batch, starts);
    k_scan<<<1, 1024, 0, stream>>>(deg, row_ptr);
    k_scatter<<<(ET + 255) / 256, 256, 0, stream>>>(ei, row_ptr, cursor, csr_src);

    dim3 gg((N_NODES + 127) / 128, NN_DIM / 128);
    dim3 gt(H_HEADS, N_NODES / 16);   // head fastest-varying -> head==XCD affinity
    int hb = (N_NODES * C_DIM / 4 + 255) / 256;

    // layer 1
    k_gemm_mfma<<<gg, 256, 0, stream>>>(xb, wt1, As_[0], Ad_[0], h, es, ed, N_NODES, IN_DIM);
    k_gat<<<gt, 256, 0, stream>>>(h, es, ed, row_ptr, csr_src, part);
    k_hsum<<<hb, 256, 0, stream>>>(part, Bi[0], Ga[0], Be[0], Mu[0], Va[0], feat_a);
    // layer 2
    k_gemm_mfma<<<gg, 256, 0, stream>>>(feat_a, wt2, As_[1], Ad_[1], h, es, ed, N_NODES, C_DIM);
    k_gat<<<gt, 256, 0, stream>>>(h, es, ed, row_ptr, csr_src, part);
    k_hsum<<<hb, 256, 0, stream>>>(part, Bi[1], Ga[1], Be[1], Mu[1], Va[1], feat_b);
    // layer 3
    k_gemm_mfma<<<gg, 256, 0, stream>>>(feat_b, wt3, As_[2], Ad_[2], h, es, ed, N_NODES, C_DIM);
    k_gat<<<gt, 256, 0, stream>>>(h, es, ed, row_ptr, csr_src, part);
    k_hsum<<<hb, 256, 0, stream>>>(part, Bi[2], Ga[2], Be[2], Mu[2], Va[2], feat_a);

    k_poolhead<<<G_GRAPHS, 1024, 0, stream>>>(feat_a, x, starts,
                                              l0W, l0b, lnW, lnb, l1W, l1b, outp);
}

// Round 8
// 194.245 us; speedup vs baseline: 1.0688x; 1.0688x over previous
//
#include <hip/hip_runtime.h>
#include <hip/hip_bf16.h>
#include <math.h>

#define N_NODES 10000
#define N_EDGES 120000
#define ET (N_EDGES + N_NODES)   // edges + self loops
#define IN_DIM 256
#define H_HEADS 8
#define C_DIM 128
#define NN_DIM (H_HEADS * C_DIM) // 1024
#define G_GRAPHS 64
#define EPS_BN 1e-5f
#define SLOPE 0.2f

typedef unsigned short u16;
typedef __attribute__((ext_vector_type(8))) short bf16x8;
typedef __attribute__((ext_vector_type(4))) float f32x4;

__device__ __forceinline__ u16 f2b(float f) {            // RNE float->bf16
    unsigned int u = __float_as_uint(f);
    unsigned int r = (u + 0x7fffu + ((u >> 16) & 1u)) >> 16;
    return (u16)r;
}
__device__ __forceinline__ float b2f(u16 u) {
    return __uint_as_float(((unsigned int)u) << 16);
}

// ---------------- fused prep: x->bf16, W->Wt bf16, degree count, graph starts ----------------
#define XB_BLOCKS 2500                        // N*IN/4/256
#define WT1_TILES 256                         // (1024/32)*(256/32)
#define WT23_TILES 128                        // (1024/32)*(128/32)
#define CNT_BLOCKS ((ET + 255) / 256)         // 508
#define ST_BLOCKS ((N_NODES + 255) / 256)     // 40
#define PREP_B0 XB_BLOCKS
#define PREP_B1 (PREP_B0 + WT1_TILES)
#define PREP_B2 (PREP_B1 + WT23_TILES)
#define PREP_B3 (PREP_B2 + WT23_TILES)
#define PREP_B4 (PREP_B3 + CNT_BLOCKS)
#define PREP_B5 (PREP_B4 + ST_BLOCKS)

__device__ __forceinline__ void wt_tile(const float* __restrict__ W, u16* __restrict__ Wt,
                                        int K, int t, int tid, float (*sh)[33]) {
    int bn = (t & 31) * 32;
    int bk = (t >> 5) * 32;
    int tx = tid & 31, ty = tid >> 5;
    for (int r = ty; r < 32; r += 8)
        sh[r][tx] = W[(size_t)(bk + r) * NN_DIM + bn + tx];   // sh[k][n]
    __syncthreads();
    for (int r = ty; r < 32; r += 8)
        Wt[(size_t)(bn + r) * K + bk + tx] = f2b(sh[tx][r]);  // Wt[n][k]
}

__global__ __launch_bounds__(256) void k_prep(const float* __restrict__ x, u16* __restrict__ xb,
                                              const float* __restrict__ W1, u16* __restrict__ wt1,
                                              const float* __restrict__ W2, u16* __restrict__ wt2,
                                              const float* __restrict__ W3, u16* __restrict__ wt3,
                                              const int* __restrict__ ei, int* __restrict__ deg,
                                              const int* __restrict__ batch, int* __restrict__ starts) {
    __shared__ float sh[32][33];
    int b = blockIdx.x, tid = threadIdx.x;
    if (b < PREP_B0) {
        int i = b * 256 + tid;                 // one float4 per thread
        float4 v = reinterpret_cast<const float4*>(x)[i];
        unsigned int lo = (unsigned int)f2b(v.x) | ((unsigned int)f2b(v.y) << 16);
        unsigned int hi = (unsigned int)f2b(v.z) | ((unsigned int)f2b(v.w) << 16);
        reinterpret_cast<uint2*>(xb)[i] = make_uint2(lo, hi);
    } else if (b < PREP_B1) {
        wt_tile(W1, wt1, IN_DIM, b - PREP_B0, tid, sh);
    } else if (b < PREP_B2) {
        wt_tile(W2, wt2, C_DIM, b - PREP_B1, tid, sh);
    } else if (b < PREP_B3) {
        wt_tile(W3, wt3, C_DIM, b - PREP_B2, tid, sh);
    } else if (b < PREP_B4) {
        int e = (b - PREP_B3) * 256 + tid;
        if (e < ET) {
            int d = (e < N_EDGES) ? ei[N_EDGES + e] : (e - N_EDGES);
            atomicAdd(&deg[d], 1);
        }
    } else {
        int i = (b - PREP_B4) * 256 + tid;
        if (i < N_NODES) {
            if (i == 0) starts[batch[0]] = 0;
            else if (batch[i] != batch[i - 1]) starts[batch[i]] = i;
            if (i == N_NODES - 1) starts[G_GRAPHS] = N_NODES;
        }
    }
}

// ---------------- single-block exclusive scan (wave shfl, 2 barriers/chunk) ----------------
__global__ __launch_bounds__(1024) void k_scan(const int* __restrict__ deg, int* __restrict__ row_ptr) {
    __shared__ int ws[16];
    __shared__ int stot;
    int tid = threadIdx.x, lane = tid & 63, wid = tid >> 6;
    int carry = 0;
    for (int base = 0; base < N_NODES; base += 1024) {
        int i = base + tid;
        int v = (i < N_NODES) ? deg[i] : 0;
        int xv = v;
        #pragma unroll
        for (int off = 1; off < 64; off <<= 1) {
            int y = __shfl_up(xv, off, 64);
            if (lane >= off) xv += y;
        }
        if (lane == 63) ws[wid] = xv;
        __syncthreads();
        if (wid == 0) {
            int t = (lane < 16) ? ws[lane] : 0;
            #pragma unroll
            for (int off = 1; off < 16; off <<= 1) {
                int y = __shfl_up(t, off, 64);
                if (lane >= off) t += y;
            }
            if (lane < 16) ws[lane] = t;
            if (lane == 15) stot = t;
        }
        __syncthreads();
        int wpref = (wid > 0) ? ws[wid - 1] : 0;
        if (i < N_NODES) row_ptr[i] = carry + wpref + xv - v;   // exclusive
        carry += stot;
        __syncthreads();    // protect ws/stot before next chunk
    }
    if (tid == 0) row_ptr[N_NODES] = carry;
}

__global__ void k_scatter(const int* __restrict__ ei, const int* __restrict__ row_ptr,
                          int* __restrict__ cursor, int* __restrict__ csr_src) {
    int e = blockIdx.x * blockDim.x + threadIdx.x;
    if (e >= ET) return;
    int s, d;
    if (e < N_EDGES) { s = ei[e]; d = ei[N_EDGES + e]; }
    else             { s = e - N_EDGES; d = s; }
    int pos = atomicAdd(&cursor[d], 1);
    csr_src[row_ptr[d] + pos] = s;
}

// ---------------- bf16 MFMA GEMM + fused es/ed epilogue ----------------
// head-major output: h[hd][n][c]; es[hd][n], ed[hd][n]; blockIdx.y == head
__global__ __launch_bounds__(256) void k_gemm_mfma(const u16* __restrict__ A,
                                                   const u16* __restrict__ Bt,
                                                   const float* __restrict__ a_s,
                                                   const float* __restrict__ a_d,
                                                   u16* __restrict__ C,
                                                   float* __restrict__ es,
                                                   float* __restrict__ ed,
                                                   int M, int K) {
    __shared__ u16 As[128 * 32];
    __shared__ u16 Bs[128 * 32];
    __shared__ float esb[2][128];
    __shared__ float edb[2][128];
    int tid = threadIdx.x;
    int wave = tid >> 6, lane = tid & 63;
    int wr = wave >> 1, wc = wave & 1;
    int bm = blockIdx.x * 128;
    int bn = blockIdx.y * 128;
    int hd = blockIdx.y;
    f32x4 acc[4][4] = {};

    for (int k0 = 0; k0 < K; k0 += 32) {
        #pragma unroll
        for (int cc = 0; cc < 2; cc++) {
            int ch = wave + cc * 4;                 // 8 chunks of 16 rows
            int row = ch * 16 + (lane >> 2);
            int gr = bm + row; if (gr >= M) gr = M - 1;
            const u16* gp = &A[(size_t)gr * K + k0 + (lane & 3) * 8];
            __builtin_amdgcn_global_load_lds((const __attribute__((address_space(1))) unsigned int*)gp,
                (__attribute__((address_space(3))) unsigned int*)&As[ch * 512], 16, 0, 0);
            const u16* gq = &Bt[(size_t)(bn + row) * K + k0 + (lane & 3) * 8];
            __builtin_amdgcn_global_load_lds((const __attribute__((address_space(1))) unsigned int*)gq,
                (__attribute__((address_space(3))) unsigned int*)&Bs[ch * 512], 16, 0, 0);
        }
        __syncthreads();
        bf16x8 af[4], bfr[4];
        #pragma unroll
        for (int mf = 0; mf < 4; mf++)
            af[mf] = *reinterpret_cast<const bf16x8*>(&As[(wr * 64 + mf * 16 + (lane & 15)) * 32 + (lane >> 4) * 8]);
        #pragma unroll
        for (int nf = 0; nf < 4; nf++)
            bfr[nf] = *reinterpret_cast<const bf16x8*>(&Bs[(wc * 64 + nf * 16 + (lane & 15)) * 32 + (lane >> 4) * 8]);
        #pragma unroll
        for (int mf = 0; mf < 4; mf++)
            #pragma unroll
            for (int nf = 0; nf < 4; nf++)
                acc[mf][nf] = __builtin_amdgcn_mfma_f32_16x16x32_bf16(af[mf], bfr[nf], acc[mf][nf], 0, 0, 0);
        __syncthreads();
    }

    // epilogue: bf16 C write (head-major) + per-row dot with a_s/a_d
    float as_v[4], ad_v[4];
    #pragma unroll
    for (int nf = 0; nf < 4; nf++) {
        int colh = wc * 64 + nf * 16 + (lane & 15);
        as_v[nf] = a_s[hd * C_DIM + colh];
        ad_v[nf] = a_d[hd * C_DIM + colh];
    }
    u16* Ch = C + (size_t)hd * M * C_DIM;
    #pragma unroll
    for (int mf = 0; mf < 4; mf++) {
        #pragma unroll
        for (int i = 0; i < 4; i++) {
            int rl = wr * 64 + mf * 16 + (lane >> 4) * 4 + i;
            int row = bm + rl;
            float se = 0.f, de = 0.f;
            #pragma unroll
            for (int nf = 0; nf < 4; nf++) {
                u16 hb = f2b(acc[mf][nf][i]);
                float vb = b2f(hb);
                se += vb * as_v[nf];
                de += vb * ad_v[nf];
                if (row < M) Ch[(size_t)row * C_DIM + wc * 64 + nf * 16 + (lane & 15)] = hb;
            }
            #pragma unroll
            for (int off = 8; off; off >>= 1) { se += __shfl_xor(se, off); de += __shfl_xor(de, off); }
            if ((lane & 15) == 0) { esb[wc][rl] = se; edb[wc][rl] = de; }
        }
    }
    __syncthreads();
    if (tid < 128) {
        int row = bm + tid;
        if (row < M) {
            es[(size_t)hd * M + row] = esb[0][tid] + esb[1][tid];
            ed[(size_t)hd * M + row] = edb[0][tid] + edb[1][tid];
        }
    }
}

// ---------------- head-affine GAT gather: single-pass (no max-sub), 4-deep unroll ----------------
// softmax is invariant to max subtraction; |alpha| <~ 3 here so exp() is safe in fp32.
// 4-deep (not 8): stays under the 64-VGPR occupancy cliff (round-7 post-mortem).
// grid (8, N/16); blockIdx.x = head (fastest-varying -> one head per XCD)
__global__ __launch_bounds__(256) void k_gat(const u16* __restrict__ h,
                                             const float* __restrict__ es,
                                             const float* __restrict__ ed,
                                             const int* __restrict__ row_ptr,
                                             const int* __restrict__ csr_src,
                                             u16* __restrict__ part) {
    int hd = blockIdx.x;
    int g = threadIdx.x >> 4;     // 16 groups
    int lane = threadIdx.x & 15;  // 16 lanes per group: 8 channels each
    int n = blockIdx.y * 16 + g;
    const u16* hh = h + (size_t)hd * N_NODES * C_DIM;
    const float* esh = es + (size_t)hd * N_NODES;
    float edv = ed[(size_t)hd * N_NODES + n];
    int s = row_ptr[n];
    int deg = row_ptr[n + 1] - s;

    __shared__ int s_src[16][16];
    __shared__ float s_p[16][16];

    float den = 0.f;
    float acc[8] = {0.f, 0.f, 0.f, 0.f, 0.f, 0.f, 0.f, 0.f};

    for (int j0 = 0; j0 < deg; j0 += 16) {
        int cn = deg - j0; if (cn > 16) cn = 16;
        if (lane < cn) {
            int src = csr_src[s + j0 + lane];
            s_src[g][lane] = src;
            float a = esh[src] + edv;
            a = (a > 0.f) ? a : SLOPE * a;
            float p = __expf(a);
            s_p[g][lane] = p;
            den += p;
        }
        int j = 0;
        for (; j + 4 <= cn; j += 4) {
            int sr0 = s_src[g][j], sr1 = s_src[g][j + 1], sr2 = s_src[g][j + 2], sr3 = s_src[g][j + 3];
            float p0 = s_p[g][j], p1 = s_p[g][j + 1], p2 = s_p[g][j + 2], p3 = s_p[g][j + 3];
            uint4 v0 = *reinterpret_cast<const uint4*>(&hh[(size_t)sr0 * C_DIM + lane * 8]);
            uint4 v1 = *reinterpret_cast<const uint4*>(&hh[(size_t)sr1 * C_DIM + lane * 8]);
            uint4 v2 = *reinterpret_cast<const uint4*>(&hh[(size_t)sr2 * C_DIM + lane * 8]);
            uint4 v3 = *reinterpret_cast<const uint4*>(&hh[(size_t)sr3 * C_DIM + lane * 8]);
            acc[0] += p0 * b2f((u16)v0.x) + p1 * b2f((u16)v1.x) + p2 * b2f((u16)v2.x) + p3 * b2f((u16)v3.x);
            acc[1] += p0 * b2f((u16)(v0.x >> 16)) + p1 * b2f((u16)(v1.x >> 16)) + p2 * b2f((u16)(v2.x >> 16)) + p3 * b2f((u16)(v3.x >> 16));
            acc[2] += p0 * b2f((u16)v0.y) + p1 * b2f((u16)v1.y) + p2 * b2f((u16)v2.y) + p3 * b2f((u16)v3.y);
            acc[3] += p0 * b2f((u16)(v0.y >> 16)) + p1 * b2f((u16)(v1.y >> 16)) + p2 * b2f((u16)(v2.y >> 16)) + p3 * b2f((u16)(v3.y >> 16));
            acc[4] += p0 * b2f((u16)v0.z) + p1 * b2f((u16)v1.z) + p2 * b2f((u16)v2.z) + p3 * b2f((u16)v3.z);
            acc[5] += p0 * b2f((u16)(v0.z >> 16)) + p1 * b2f((u16)(v1.z >> 16)) + p2 * b2f((u16)(v2.z >> 16)) + p3 * b2f((u16)(v3.z >> 16));
            acc[6] += p0 * b2f((u16)v0.w) + p1 * b2f((u16)v1.w) + p2 * b2f((u16)v2.w) + p3 * b2f((u16)v3.w);
            acc[7] += p0 * b2f((u16)(v0.w >> 16)) + p1 * b2f((u16)(v1.w >> 16)) + p2 * b2f((u16)(v2.w >> 16)) + p3 * b2f((u16)(v3.w >> 16));
        }
        for (; j < cn; j++) {
            int sr = s_src[g][j];
            float p = s_p[g][j];
            uint4 v = *reinterpret_cast<const uint4*>(&hh[(size_t)sr * C_DIM + lane * 8]);
            acc[0] += p * b2f((u16)v.x);
            acc[1] += p * b2f((u16)(v.x >> 16));
            acc[2] += p * b2f((u16)v.y);
            acc[3] += p * b2f((u16)(v.y >> 16));
            acc[4] += p * b2f((u16)v.z);
            acc[5] += p * b2f((u16)(v.z >> 16));
            acc[6] += p * b2f((u16)v.w);
            acc[7] += p * b2f((u16)(v.w >> 16));
        }
    }
    #pragma unroll
    for (int off = 8; off; off >>= 1) den += __shfl_xor(den, off, 16);
    float inv = 1.f / den;
    unsigned int w0 = (unsigned int)f2b(acc[0] * inv) | ((unsigned int)f2b(acc[1] * inv) << 16);
    unsigned int w1 = (unsigned int)f2b(acc[2] * inv) | ((unsigned int)f2b(acc[3] * inv) << 16);
    unsigned int w2 = (unsigned int)f2b(acc[4] * inv) | ((unsigned int)f2b(acc[5] * inv) << 16);
    unsigned int w3 = (unsigned int)f2b(acc[6] * inv) | ((unsigned int)f2b(acc[7] * inv) << 16);
    *reinterpret_cast<uint4*>(&part[((size_t)hd * N_NODES + n) * C_DIM + lane * 8]) =
        make_uint4(w0, w1, w2, w3);
}

// ---------------- head-sum + mean + bias + relu + BN -> feat (bf16) ----------------
__global__ __launch_bounds__(256) void k_hsum(const u16* __restrict__ part,
                                              const float* __restrict__ bias,
                                              const float* __restrict__ gamma,
                                              const float* __restrict__ beta,
                                              const float* __restrict__ rmean,
                                              const float* __restrict__ rvar,
                                              u16* __restrict__ feat) {
    int idx = blockIdx.x * blockDim.x + threadIdx.x;   // one per (n, 4-ch quad)
    int n = idx >> 5;
    int q = idx & 31;
    int c = q * 4;
    float s0 = 0.f, s1 = 0.f, s2 = 0.f, s3 = 0.f;
    #pragma unroll
    for (int hd = 0; hd < H_HEADS; hd++) {
        uint2 v = *reinterpret_cast<const uint2*>(&part[((size_t)hd * N_NODES + n) * C_DIM + c]);
        s0 += b2f((u16)v.x); s1 += b2f((u16)(v.x >> 16));
        s2 += b2f((u16)v.y); s3 += b2f((u16)(v.y >> 16));
    }
    float4 bi = *reinterpret_cast<const float4*>(&bias[c]);
    float4 ga = *reinterpret_cast<const float4*>(&gamma[c]);
    float4 be = *reinterpret_cast<const float4*>(&beta[c]);
    float4 mu = *reinterpret_cast<const float4*>(&rmean[c]);
    float4 va = *reinterpret_cast<const float4*>(&rvar[c]);
    float v0 = fmaxf(s0 * 0.125f + bi.x, 0.f);
    float v1 = fmaxf(s1 * 0.125f + bi.y, 0.f);
    float v2 = fmaxf(s2 * 0.125f + bi.z, 0.f);
    float v3 = fmaxf(s3 * 0.125f + bi.w, 0.f);
    v0 = (v0 - mu.x) * rsqrtf(va.x + EPS_BN) * ga.x + be.x;
    v1 = (v1 - mu.y) * rsqrtf(va.y + EPS_BN) * ga.y + be.y;
    v2 = (v2 - mu.z) * rsqrtf(va.z + EPS_BN) * ga.z + be.z;
    v3 = (v3 - mu.w) * rsqrtf(va.w + EPS_BN) * ga.w + be.w;
    unsigned int lo = (unsigned int)f2b(v0) | ((unsigned int)f2b(v1) << 16);
    unsigned int hi = (unsigned int)f2b(v2) | ((unsigned int)f2b(v3) << 16);
    *reinterpret_cast<uint2*>(&feat[(size_t)n * C_DIM + c]) = make_uint2(lo, hi);
}

// ---------------- fused pooling + MLP head: 1024 threads, 8-way k-split ----------------
__global__ __launch_bounds__(1024) void k_poolhead(const u16* __restrict__ feat,
                                                   const float* __restrict__ x,
                                                   const int* __restrict__ starts,
                                                   const float* __restrict__ l0W, const float* __restrict__ l0b,
                                                   const float* __restrict__ lnW, const float* __restrict__ lnb,
                                                   const float* __restrict__ l1W, const float* __restrict__ l1b,
                                                   float* __restrict__ outp) {
    int g = blockIdx.x;
    int tid = threadIdx.x;
    int part = tid >> 7;               // 0..7
    int c = tid & 127;
    int s = starts[g], e = starts[g + 1];

    __shared__ float smx[8][128], ssm[8][128];
    __shared__ float pg[256];
    __shared__ float xr[256];
    __shared__ float sh2[2];

    // pooling: 8-way strided over nodes
    float mx = -1e30f, sm = 0.f;
    for (int i = s + part; i < e; i += 8) {
        float v = b2f(feat[(size_t)i * C_DIM + c]);
        mx = fmaxf(mx, v);
        sm += v;
    }
    smx[part][c] = mx;
    ssm[part][c] = sm;
    if (tid < 256) xr[tid] = x[(size_t)s * IN_DIM + tid];   // root row
    __syncthreads();
    if (part == 0) {
        float m = smx[0][c], t = ssm[0][c];
        #pragma unroll
        for (int p2 = 1; p2 < 8; p2++) { m = fmaxf(m, smx[p2][c]); t += ssm[p2][c]; }
        pg[c] = m;
        pg[128 + c] = t / (float)(e - s);
    }
    __syncthreads();

    // head GEMMs: k-split 8 x 32
    float acc0 = 0.f, acc1 = 0.f;
    int k0 = part * 32;
    #pragma unroll 8
    for (int k = k0; k < k0 + 32; k++) {
        acc0 += pg[k] * l0W[k * C_DIM + c];
        acc1 += xr[k] * lnW[k * C_DIM + c];
    }
    __syncthreads();                     // pg/xr reads done; reuse smx/ssm
    smx[part][c] = acc0;
    ssm[part][c] = acc1;
    __syncthreads();
    if (part == 0) {                     // first 2 waves finish
        float a0 = 0.f, a1 = 0.f;
        #pragma unroll
        for (int p2 = 0; p2 < 8; p2++) { a0 += smx[p2][c]; a1 += ssm[p2][c]; }
        float hg = fmaxf(a0 + l0b[c], 0.f);
        float nw = fmaxf(a1 + lnb[c], 0.f);
        float prt = hg * l1W[c] + nw * l1W[C_DIM + c];
        #pragma unroll
        for (int off = 32; off; off >>= 1) prt += __shfl_down(prt, off, 64);
        if ((c & 63) == 0) sh2[c >> 6] = prt;
    }
    __syncthreads();
    if (tid == 0) {
        float t = sh2[0] + sh2[1] + l1b[0];
        outp[g] = 1.f / (1.f + __expf(-t));
    }
}

extern "C" void kernel_launch(void* const* d_in, const int* in_sizes, int n_in,
                              void* d_out, int out_size, void* d_ws, size_t ws_size,
                              hipStream_t stream) {
    const float* x   = (const float*)d_in[0];
    const int* ei    = (const int*)d_in[1];
    const int* batch = (const int*)d_in[2];
    const float* W[3];  const float* As_[3]; const float* Ad_[3];
    const float* Bi[3]; const float* Ga[3]; const float* Be[3];
    const float* Mu[3]; const float* Va[3];
    for (int l = 0; l < 3; l++) {
        int base = 3 + 8 * l;
        W[l]   = (const float*)d_in[base + 0];
        As_[l] = (const float*)d_in[base + 1];
        Ad_[l] = (const float*)d_in[base + 2];
        Bi[l]  = (const float*)d_in[base + 3];
        Ga[l]  = (const float*)d_in[base + 4];
        Be[l]  = (const float*)d_in[base + 5];
        Mu[l]  = (const float*)d_in[base + 6];
        Va[l]  = (const float*)d_in[base + 7];
    }
    const float* lnW = (const float*)d_in[27];
    const float* lnb = (const float*)d_in[28];
    const float* l0W = (const float*)d_in[29];
    const float* l0b = (const float*)d_in[30];
    const float* l1W = (const float*)d_in[31];
    const float* l1b = (const float*)d_in[32];
    float* outp = (float*)d_out;

    // workspace layout (all offsets 16B-aligned)
    char* p = (char*)d_ws;
    auto take = [&](size_t bytes) { char* q = p; p += (bytes + 15) & ~(size_t)15; return q; };
    u16*  h      = (u16*)take((size_t)N_NODES * NN_DIM * sizeof(u16));   // head-major [hd][n][c]
    u16*  part   = (u16*)take((size_t)N_NODES * NN_DIM * sizeof(u16));   // head-major partial out
    u16*  xb     = (u16*)take((size_t)N_NODES * IN_DIM * sizeof(u16));
    u16*  wt1    = (u16*)take((size_t)NN_DIM * IN_DIM * sizeof(u16));
    u16*  wt2    = (u16*)take((size_t)NN_DIM * C_DIM * sizeof(u16));
    u16*  wt3    = (u16*)take((size_t)NN_DIM * C_DIM * sizeof(u16));
    u16*  feat_a = (u16*)take((size_t)N_NODES * C_DIM * sizeof(u16));
    u16*  feat_b = (u16*)take((size_t)N_NODES * C_DIM * sizeof(u16));
    float* es    = (float*)take((size_t)N_NODES * H_HEADS * sizeof(float));  // [hd][n]
    float* ed    = (float*)take((size_t)N_NODES * H_HEADS * sizeof(float));  // [hd][n]
    int* deg     = (int*)take((size_t)N_NODES * sizeof(int));      // deg+cursor adjacent:
    int* cursor  = (int*)take((size_t)N_NODES * sizeof(int));      // single memset below
    int* row_ptr = (int*)take((size_t)(N_NODES + 1) * sizeof(int));
    int* csr_src = (int*)take((size_t)ET * sizeof(int));
    int* starts  = (int*)take((size_t)(G_GRAPHS + 1) * sizeof(int));

    hipMemsetAsync(deg, 0, 2 * N_NODES * sizeof(int), stream);   // deg + cursor

    // prep (x->bf16, Wt transposes, degree count, graph starts) + CSR
    k_prep<<<PREP_B5, 256, 0, stream>>>(x, xb, W[0], wt1, W[1], wt2, W[2], wt3,
                                        ei, deg, batch, starts);
    k_scan<<<1, 1024, 0, stream>>>(deg, row_ptr);
    k_scatter<<<(ET + 255) / 256, 256, 0, stream>>>(ei, row_ptr, cursor, csr_src);

    dim3 gg((N_NODES + 127) / 128, NN_DIM / 128);
    dim3 gt(H_HEADS, N_NODES / 16);   // head fastest-varying -> head==XCD affinity
    int hb = (N_NODES * C_DIM / 4 + 255) / 256;

    // layer 1
    k_gemm_mfma<<<gg, 256, 0, stream>>>(xb, wt1, As_[0], Ad_[0], h, es, ed, N_NODES, IN_DIM);
    k_gat<<<gt, 256, 0, stream>>>(h, es, ed, row_ptr, csr_src, part);
    k_hsum<<<hb, 256, 0, stream>>>(part, Bi[0], Ga[0], Be[0], Mu[0], Va[0], feat_a);
    // layer 2
    k_gemm_mfma<<<gg, 256, 0, stream>>>(feat_a, wt2, As_[1], Ad_[1], h, es, ed, N_NODES, C_DIM);
    k_gat<<<gt, 256, 0, stream>>>(h, es, ed, row_ptr, csr_src, part);
    k_hsum<<<hb, 256, 0, stream>>>(part, Bi[1], Ga[1], Be[1], Mu[1], Va[1], feat_b);
    // layer 3
    k_gemm_mfma<<<gg, 256, 0, stream>>>(feat_b, wt3, As_[2], Ad_[2], h, es, ed, N_NODES, C_DIM);
    k_gat<<<gt, 256, 0, stream>>>(h, es, ed, row_ptr, csr_src, part);
    k_hsum<<<hb, 256, 0, stream>>>(part, Bi[2], Ga[2], Be[2], Mu[2], Va[2], feat_a);

    k_poolhead<<<G_GRAPHS, 1024, 0, stream>>>(feat_a, x, starts,
                                              l0W, l0b, lnW, lnb, l1W, l1b, outp);
}